// Round 4
// baseline (818.810 us; speedup 1.0000x reference)
//
#include <hip/hip_runtime.h>
#include <stdint.h>

#define DIMD 4096   // feature width (and K)
#define DIMB 4096   // batch
#define NLAYER 4
#define NT (DIMD / 64)   // 64 K-tiles of BK=64

typedef unsigned short u16;
typedef __attribute__((ext_vector_type(16))) float f32x16;
typedef __attribute__((ext_vector_type(8))) __bf16 bf16x8;

__device__ __forceinline__ u16 f2bf(float f) {
    union { float f; uint32_t u; } v; v.f = f;
    return (u16)((v.u + 0x7fffu + ((v.u >> 16) & 1u)) >> 16);  // RNE
}

// ---------------- fp32 -> bf16 elementwise (x input) ----------------
__global__ void k_cvt(const float* __restrict__ in, u16* __restrict__ out) {
    int i = (blockIdx.x * 256 + threadIdx.x) * 4;
    float4 v = *reinterpret_cast<const float4*>(in + i);
    ushort4 r;
    r.x = f2bf(v.x); r.y = f2bf(v.y); r.z = f2bf(v.z); r.w = f2bf(v.w);
    *reinterpret_cast<ushort4*>(out + i) = r;
}

// ------- W[l][k][n] fp32 -> Wt4[l][n][k] bf16, all 4 layers in one launch -------
__global__ void k_trans(const float* __restrict__ W, u16* __restrict__ Wt) {
    __shared__ float tile[64][65];
    const int t = threadIdx.x;
    const size_t loff = (size_t)blockIdx.z * DIMD * DIMD;
    const int n0 = blockIdx.x * 64, k0 = blockIdx.y * 64;
    const int kr = t >> 4, c4 = (t & 15) * 4;
    #pragma unroll
    for (int r = 0; r < 4; ++r) {
        float4 v = *reinterpret_cast<const float4*>(W + loff + (size_t)(k0 + kr + r * 16) * DIMD + n0 + c4);
        tile[kr + r * 16][c4 + 0] = v.x;
        tile[kr + r * 16][c4 + 1] = v.y;
        tile[kr + r * 16][c4 + 2] = v.z;
        tile[kr + r * 16][c4 + 3] = v.w;
    }
    __syncthreads();
    const int nr = t >> 4, k4 = (t & 15) * 4;
    #pragma unroll
    for (int r = 0; r < 4; ++r) {
        int n = nr + r * 16;
        ushort4 o;
        o.x = f2bf(tile[k4 + 0][n]);
        o.y = f2bf(tile[k4 + 1][n]);
        o.z = f2bf(tile[k4 + 2][n]);
        o.w = f2bf(tile[k4 + 3][n]);
        *reinterpret_cast<ushort4*>(Wt + loff + (size_t)(n0 + n) * DIMD + k0 + k4) = o;
    }
}

// ---------------- 256x256 8-phase bf16 MFMA GEMM (32x32x16) ----------------
// BM=BN=256, BK=64, 512 threads = 8 waves (2M x 4N), per-wave 128x64 output as
// 4x2 frags of 32x32 (acc f32x16). LDS double-buffered 128 KiB, XOR chunk
// swizzle (chunk' = chunk ^ (row&7), 16B chunks) on pre-swizzled global source
// + ds_read address. Counted-vmcnt pipeline: stage tile t+2's B at P3(t), A at
// P4(t); one vmcnt(8)/tile (issue->drain = 4-5 phases). Region safety: B(t)
// fully read after P2, A(t) after P3.
#define GLD(g, l) __builtin_amdgcn_global_load_lds( \
    (__attribute__((address_space(1))) void*)(g),   \
    (__attribute__((address_space(3))) void*)(l), 16, 0, 0)

__global__ __launch_bounds__(512, 2) void k_gemm(
        const u16* __restrict__ A, const u16* __restrict__ Bt,
        const float* __restrict__ bias, float* __restrict__ C,
        float* __restrict__ csum, float* __restrict__ csum2) {
    __shared__ __attribute__((aligned(16))) u16 As[2 * 256 * 64];   // 64 KiB
    __shared__ __attribute__((aligned(16))) u16 Bs[2 * 256 * 64];   // 64 KiB
    const int tid = threadIdx.x;
    const int lane = tid & 63, wv = tid >> 6;
    const int wm = wv >> 2, wn = wv & 3;          // 2 x 4 wave grid
    const int bm = blockIdx.y, bn = blockIdx.x;
    const int lc = lane & 31, lh = lane >> 5;     // 32x32 frag: row/col = lc, k-half = lh

    // ---- staging geometry: per GLD issue, 512 threads x 16B cover 64 rows x 64 cols
    const int r0 = tid >> 3;                       // 0..63
    const int cswz = (tid & 7) ^ (r0 & 7);         // inverse-swizzled 16B chunk
    const u16* gA = A  + (size_t)(bm * 256 + r0) * DIMD + cswz * 8;
    const u16* gB = Bt + (size_t)(bn * 256 + r0) * DIMD + cswz * 8;

    // unit = one matrix half (128 rows x 64 cols = 16 KiB = 2 GLD issues)
#define STAGE_A(h, t, buf) do { \
    const u16* _s = gA + (size_t)(h) * 128 * DIMD + (size_t)(t) * 64; \
    u16* _d = As + (buf) * 16384 + (h) * 8192 + wv * 512; \
    GLD(_s, _d); GLD(_s + (size_t)64 * DIMD, _d + 4096); \
} while (0)
#define STAGE_B(h, t, buf) do { \
    const u16* _s = gB + (size_t)(h) * 128 * DIMD + (size_t)(t) * 64; \
    u16* _d = Bs + (buf) * 16384 + (h) * 8192 + wv * 512; \
    GLD(_s, _d); GLD(_s + (size_t)64 * DIMD, _d + 4096); \
} while (0)

    // ---- ds_read fragment offsets (u16 units), swizzled
    // A row = wm*128 + mf*32 + lc ; chunk = ks*2 + lh (k = ks*16 + lh*8 + i)
    int aoff[4][4], boff[2][4];
    #pragma unroll
    for (int mf = 0; mf < 4; ++mf)
        #pragma unroll
        for (int ks = 0; ks < 4; ++ks) {
            int row = wm * 128 + mf * 32 + lc;
            aoff[mf][ks] = row * 64 + ((ks * 2 + lh) ^ (row & 7)) * 8;
        }
    #pragma unroll
    for (int nf = 0; nf < 2; ++nf)
        #pragma unroll
        for (int ks = 0; ks < 4; ++ks) {
            int row = wn * 64 + nf * 32 + lc;
            boff[nf][ks] = row * 64 + ((ks * 2 + lh) ^ (row & 7)) * 8;
        }

    f32x16 acc[4][2] = {};         // [mf][nf]
    bf16x8 a[2][4], b0[4], b1[4];  // a: 2 row-frags x 4 ks (reused P1/P3)

    // ---- prologue: tiles 0 and 1 fully issued; drain tile 0, keep tile 1 in flight
    STAGE_B(0, 0, 0); STAGE_B(1, 0, 0); STAGE_A(0, 0, 0); STAGE_A(1, 0, 0);
    STAGE_B(0, 1, 1); STAGE_B(1, 1, 1); STAGE_A(0, 1, 1); STAGE_A(1, 1, 1);
    asm volatile("s_waitcnt vmcnt(8)" ::: "memory");
    __builtin_amdgcn_s_barrier();

    for (int t = 0; t < NT; ++t) {
        const int cur = t & 1;
        const u16* Ab = As + cur * 16384;
        const u16* Bb = Bs + cur * 16384;
        const bool pf = (t + 2 < NT);

        // ===== P1: read a(mf0,1)+b0; MFMA frags (mf0..1, nf0)
        #pragma unroll
        for (int mf = 0; mf < 2; ++mf)
            #pragma unroll
            for (int ks = 0; ks < 4; ++ks)
                a[mf][ks] = *reinterpret_cast<const bf16x8*>(Ab + aoff[mf][ks]);
        #pragma unroll
        for (int ks = 0; ks < 4; ++ks)
            b0[ks] = *reinterpret_cast<const bf16x8*>(Bb + boff[0][ks]);
        __builtin_amdgcn_s_barrier();
        asm volatile("s_waitcnt lgkmcnt(0)" ::: "memory");
        __builtin_amdgcn_s_setprio(1);
        #pragma unroll
        for (int ks = 0; ks < 4; ++ks)
            #pragma unroll
            for (int mf = 0; mf < 2; ++mf)
                acc[mf][0] = __builtin_amdgcn_mfma_f32_32x32x16_bf16(
                    a[mf][ks], b0[ks], acc[mf][0], 0, 0, 0);
        __builtin_amdgcn_s_setprio(0);
        __builtin_amdgcn_s_barrier();

        // ===== P2: read b1; MFMA frags (mf0..1, nf1)
        #pragma unroll
        for (int ks = 0; ks < 4; ++ks)
            b1[ks] = *reinterpret_cast<const bf16x8*>(Bb + boff[1][ks]);
        __builtin_amdgcn_s_barrier();
        asm volatile("s_waitcnt lgkmcnt(0)" ::: "memory");
        __builtin_amdgcn_s_setprio(1);
        #pragma unroll
        for (int ks = 0; ks < 4; ++ks)
            #pragma unroll
            for (int mf = 0; mf < 2; ++mf)
                acc[mf][1] = __builtin_amdgcn_mfma_f32_32x32x16_bf16(
                    a[mf][ks], b1[ks], acc[mf][1], 0, 0, 0);
        __builtin_amdgcn_s_setprio(0);
        __builtin_amdgcn_s_barrier();

        // ===== P3: read a(mf2,3); stage B(t+2) into cur (B reads done at P2);
        //           MFMA frags (mf2..3, nf1)
        #pragma unroll
        for (int mf = 0; mf < 2; ++mf)
            #pragma unroll
            for (int ks = 0; ks < 4; ++ks)
                a[mf][ks] = *reinterpret_cast<const bf16x8*>(Ab + aoff[2 + mf][ks]);
        if (pf) { STAGE_B(0, t + 2, cur); STAGE_B(1, t + 2, cur); }
        __builtin_amdgcn_s_barrier();
        asm volatile("s_waitcnt lgkmcnt(0)" ::: "memory");
        __builtin_amdgcn_s_setprio(1);
        #pragma unroll
        for (int ks = 0; ks < 4; ++ks)
            #pragma unroll
            for (int mf = 0; mf < 2; ++mf)
                acc[2 + mf][1] = __builtin_amdgcn_mfma_f32_32x32x16_bf16(
                    a[mf][ks], b1[ks], acc[2 + mf][1], 0, 0, 0);
        __builtin_amdgcn_s_setprio(0);
        __builtin_amdgcn_s_barrier();

        // ===== P4: stage A(t+2) into cur (A reads done at P3);
        //           MFMA frags (mf2..3, nf0) reusing b0; counted vmcnt; tile-end barrier
        if (pf) { STAGE_A(0, t + 2, cur); STAGE_A(1, t + 2, cur); }
        __builtin_amdgcn_s_setprio(1);
        #pragma unroll
        for (int ks = 0; ks < 4; ++ks)
            #pragma unroll
            for (int mf = 0; mf < 2; ++mf)
                acc[2 + mf][0] = __builtin_amdgcn_mfma_f32_32x32x16_bf16(
                    a[mf][ks], b0[ks], acc[2 + mf][0], 0, 0, 0);
        __builtin_amdgcn_s_setprio(0);
        if (pf) asm volatile("s_waitcnt vmcnt(8)" ::: "memory");
        else    asm volatile("s_waitcnt vmcnt(0)" ::: "memory");
        __builtin_amdgcn_s_barrier();
    }

    // ---- epilogue: bias, fp32 C, BN stats
    // 32x32 C/D: col = lane&31, row = (reg&3) + 8*(reg>>2) + 4*(lane>>5)
    #pragma unroll
    for (int nf = 0; nf < 2; ++nf) {
        int col = bn * 256 + wn * 64 + nf * 32 + lc;
        float bv = bias[col];
        float s1 = 0.f, s2 = 0.f;
        #pragma unroll
        for (int mf = 0; mf < 4; ++mf) {
            int rbase = bm * 256 + wm * 128 + mf * 32 + lh * 4;
            #pragma unroll
            for (int r = 0; r < 16; ++r) {
                int row = rbase + (r & 3) + 8 * (r >> 2);
                float v = acc[mf][nf][r] + bv;
                C[(size_t)row * DIMD + col] = v;
                s1 += v; s2 += v * v;
            }
        }
        s1 += __shfl_xor(s1, 32);
        s2 += __shfl_xor(s2, 32);
        if (lh == 0) {
            atomicAdd(&csum[col], s1);
            atomicAdd(&csum2[col], s2);
        }
    }
#undef STAGE_A
#undef STAGE_B
}

// ------- normalize + relu -> bf16 (layers 0..2); BN finalize fused -------
__global__ void k_norm(const float* __restrict__ H, const float* __restrict__ sum,
                       const float* __restrict__ sum2, const float* __restrict__ gamma,
                       const float* __restrict__ beta, u16* __restrict__ o) {
    int j = blockIdx.x * 256 + threadIdx.x;
    int i0 = blockIdx.y * 128;
    float mu = sum[j] * (1.0f / DIMB);
    float var = sum2[j] * (1.0f / DIMB) - mu * mu;
    float sj = gamma[j] * rsqrtf(var + 1e-5f);
    float tj = beta[j] - mu * sj;
    for (int i = i0; i < i0 + 128; ++i) {
        float v = fmaxf(H[(size_t)i * DIMD + j] * sj + tj, 0.0f);
        o[(size_t)i * DIMD + j] = f2bf(v);
    }
}

// ------- layer 3: normalize + relu + exp in place, column exp-sums -------
__global__ void k_normexp(float* __restrict__ H, const float* __restrict__ sum,
                          const float* __restrict__ sum2, const float* __restrict__ gamma,
                          const float* __restrict__ beta, float* __restrict__ esum) {
    int j = blockIdx.x * 256 + threadIdx.x;
    int i0 = blockIdx.y * 128;
    float mu = sum[j] * (1.0f / DIMB);
    float var = sum2[j] * (1.0f / DIMB) - mu * mu;
    float sj = gamma[j] * rsqrtf(var + 1e-5f);
    float tj = beta[j] - mu * sj;
    float acc = 0.f;
    for (int i = i0; i < i0 + 128; ++i) {
        float v = fmaxf(H[(size_t)i * DIMD + j] * sj + tj, 0.0f);
        float e = __expf(v);          // v in [0,~8]: no overflow, max-subtract unnecessary
        H[(size_t)i * DIMD + j] = e;
        acc += e;
    }
    atomicAdd(&esum[j], acc);
}

// ---------------- softmax divide, in place ----------------
__global__ void k_div(float* __restrict__ H, const float* __restrict__ esum) {
    int i = (blockIdx.x * 256 + threadIdx.x) * 4;
    float4 v = *reinterpret_cast<const float4*>(H + i);
    const float4 e = *reinterpret_cast<const float4*>(esum + (i & (DIMD - 1)));
    v.x /= e.x; v.y /= e.y; v.z /= e.z; v.w /= e.w;
    *reinterpret_cast<float4*>(H + i) = v;
}

extern "C" void kernel_launch(void* const* d_in, const int* in_sizes, int n_in,
                              void* d_out, int out_size, void* d_ws, size_t ws_size,
                              hipStream_t stream) {
    (void)in_sizes; (void)n_in; (void)out_size; (void)ws_size;
    const float* x     = (const float*)d_in[0];
    const float* W     = (const float*)d_in[1];
    const float* b     = (const float*)d_in[2];
    const float* gamma = (const float*)d_in[3];
    const float* beta  = (const float*)d_in[4];
    float* out = (float*)d_out;                       // doubles as H scratch (fp32 4096x4096)

    char* ws = (char*)d_ws;                               // ws >= 1 GiB (observed)
    u16*  Abf = (u16*)ws;                                 // 32 MiB activation bf16
    u16*  Wt4 = (u16*)(ws + (size_t)32 * 1024 * 1024);    // 4 x 32 MiB transposed weights
    float* stats = (float*)(ws + (size_t)160 * 1024 * 1024);
    // stats: per layer l: sum = stats + l*8192, sum2 = sum + 4096; esum = stats + 32768
    hipMemsetAsync(stats, 0, (4 * 8192 + 4096) * sizeof(float), stream);

    k_cvt<<<DIMB * DIMD / 1024, 256, 0, stream>>>(x, Abf);
    k_trans<<<dim3(64, 64, 4), 256, 0, stream>>>(W, Wt4);

    for (int l = 0; l < NLAYER; ++l) {
        float* sum = stats + l * 8192;
        float* sum2 = sum + 4096;
        k_gemm<<<dim3(16, 16), 512, 0, stream>>>(Abf, Wt4 + (size_t)l * DIMD * DIMD,
                                                 b + l * DIMD, out, sum, sum2);
        if (l < NLAYER - 1)
            k_norm<<<dim3(16, 32), 256, 0, stream>>>(out, sum, sum2,
                gamma + l * DIMD, beta + l * DIMD, Abf);
        else
            k_normexp<<<dim3(16, 32), 256, 0, stream>>>(out, sum, sum2,
                gamma + l * DIMD, beta + l * DIMD, stats + 32768);
    }
    k_div<<<DIMB * DIMD / 1024, 256, 0, stream>>>(out, stats + 32768);
}

// Round 5
// 793.414 us; speedup vs baseline: 1.0320x; 1.0320x over previous
//
#include <hip/hip_runtime.h>
#include <stdint.h>

#define DIMD 4096   // feature width (and K)
#define DIMB 4096   // batch
#define NLAYER 4
#define NT (DIMD / 64)   // 64 K-tiles of BK=64

typedef unsigned short u16;
typedef __attribute__((ext_vector_type(4))) float f32x4;
typedef __attribute__((ext_vector_type(8))) __bf16 bf16x8;

__device__ __forceinline__ u16 f2bf(float f) {
    union { float f; uint32_t u; } v; v.f = f;
    return (u16)((v.u + 0x7fffu + ((v.u >> 16) & 1u)) >> 16);  // RNE
}

// ---------------- fp32 -> bf16 elementwise (x input) ----------------
__global__ void k_cvt(const float* __restrict__ in, u16* __restrict__ out) {
    int i = (blockIdx.x * 256 + threadIdx.x) * 4;
    float4 v = *reinterpret_cast<const float4*>(in + i);
    ushort4 r;
    r.x = f2bf(v.x); r.y = f2bf(v.y); r.z = f2bf(v.z); r.w = f2bf(v.w);
    *reinterpret_cast<ushort4*>(out + i) = r;
}

// ------- W[l][k][n] fp32 -> Wt4[l][n][k] bf16, all 4 layers in one launch -------
__global__ void k_trans(const float* __restrict__ W, u16* __restrict__ Wt) {
    __shared__ float tile[64][65];
    const int t = threadIdx.x;
    const size_t loff = (size_t)blockIdx.z * DIMD * DIMD;
    const int n0 = blockIdx.x * 64, k0 = blockIdx.y * 64;
    const int kr = t >> 4, c4 = (t & 15) * 4;
    #pragma unroll
    for (int r = 0; r < 4; ++r) {
        float4 v = *reinterpret_cast<const float4*>(W + loff + (size_t)(k0 + kr + r * 16) * DIMD + n0 + c4);
        tile[kr + r * 16][c4 + 0] = v.x;
        tile[kr + r * 16][c4 + 1] = v.y;
        tile[kr + r * 16][c4 + 2] = v.z;
        tile[kr + r * 16][c4 + 3] = v.w;
    }
    __syncthreads();
    const int nr = t >> 4, k4 = (t & 15) * 4;
    #pragma unroll
    for (int r = 0; r < 4; ++r) {
        int n = nr + r * 16;
        ushort4 o;
        o.x = f2bf(tile[k4 + 0][n]);
        o.y = f2bf(tile[k4 + 1][n]);
        o.z = f2bf(tile[k4 + 2][n]);
        o.w = f2bf(tile[k4 + 3][n]);
        *reinterpret_cast<ushort4*>(Wt + loff + (size_t)(n0 + n) * DIMD + k0 + k4) = o;
    }
}

// ------------- 256x256 pipelined bf16 MFMA GEMM (16x16x32 frags) -------------
// BM=BN=256, BK=64, 512 threads = 8 waves (2M x 4N), per-wave 128x64 output as
// 8x4 frags of 16x16 (proven conflict-free swizzle: chunk' = chunk ^ (row&7)).
// Intra-tile software pipeline, 2 barriers/tile:
//   R1(a-lo,b0) R2(b1) | MFMA1 | R3(a-hi) | MFMA2 | lgkm(0)+SB(0); bar;
//   stage(t+2)->cur | MFMA3 | MFMA4 | vmcnt(8); bar
// WAR safety: stage(t+2) writes buffer cur, issued only after the barrier that
// follows every wave's lgkmcnt(0) (all reads of cur complete). Staging of tile
// t drained by tile (t-1)'s end vmcnt(8) (8 = tile t+1's GLDs still in flight).
#define GLD(g, l) __builtin_amdgcn_global_load_lds( \
    (__attribute__((address_space(1))) void*)(g),   \
    (__attribute__((address_space(3))) void*)(l), 16, 0, 0)

__global__ __launch_bounds__(512, 2) void k_gemm(
        const u16* __restrict__ A, const u16* __restrict__ Bt,
        const float* __restrict__ bias, float* __restrict__ C,
        float* __restrict__ csum, float* __restrict__ csum2) {
    __shared__ __attribute__((aligned(16))) u16 As[2 * 256 * 64];   // 64 KiB
    __shared__ __attribute__((aligned(16))) u16 Bs[2 * 256 * 64];   // 64 KiB
    const int tid = threadIdx.x;
    const int lane = tid & 63, wv = tid >> 6;
    const int wm = wv >> 2, wn = wv & 3;          // 2 x 4 wave grid
    const int bm = blockIdx.y, bn = blockIdx.x;
    const int lr = lane & 15, lk = lane >> 4;

    // ---- staging geometry: per GLD issue, 512 threads x 16B cover 64 rows x 64 cols
    const int r0 = tid >> 3;                       // 0..63
    const int cswz = (tid & 7) ^ (r0 & 7);         // inverse-swizzled 16B chunk
    const u16* gA = A  + (size_t)(bm * 256 + r0) * DIMD + cswz * 8;
    const u16* gB = Bt + (size_t)(bn * 256 + r0) * DIMD + cswz * 8;

    // unit = one matrix half (128 rows x 64 cols = 16 KiB = 2 GLD issues)
#define STAGE_A(h, t, buf) do { \
    const u16* _s = gA + (size_t)(h) * 128 * DIMD + (size_t)(t) * 64; \
    u16* _d = As + (buf) * 16384 + (h) * 8192 + wv * 512; \
    GLD(_s, _d); GLD(_s + (size_t)64 * DIMD, _d + 4096); \
} while (0)
#define STAGE_B(h, t, buf) do { \
    const u16* _s = gB + (size_t)(h) * 128 * DIMD + (size_t)(t) * 64; \
    u16* _d = Bs + (buf) * 16384 + (h) * 8192 + wv * 512; \
    GLD(_s, _d); GLD(_s + (size_t)64 * DIMD, _d + 4096); \
} while (0)

    // ---- ds_read fragment offsets (u16 units), swizzled (conflict-free, r1 proven)
    int aoff[4][2], boff[2][2];
    #pragma unroll
    for (int mf = 0; mf < 4; ++mf)
        #pragma unroll
        for (int ks = 0; ks < 2; ++ks) {
            int row = wm * 128 + mf * 16 + lr;
            aoff[mf][ks] = row * 64 + ((ks * 4 + lk) ^ (row & 7)) * 8;
        }
    #pragma unroll
    for (int nf = 0; nf < 2; ++nf)
        #pragma unroll
        for (int ks = 0; ks < 2; ++ks) {
            int row = wn * 64 + nf * 16 + lr;
            boff[nf][ks] = row * 64 + ((ks * 4 + lk) ^ (row & 7)) * 8;
        }

    f32x4 acc[8][4] = {};          // [mh*4+mf][nh*2+nf]
    bf16x8 al[4][2], ah[4][2], b0[2][2], b1[2][2];

    // ---- prologue: tiles 0 and 1 fully issued; drain tile 0, keep tile 1 in flight
    STAGE_B(0, 0, 0); STAGE_B(1, 0, 0); STAGE_A(0, 0, 0); STAGE_A(1, 0, 0);
    STAGE_B(0, 1, 1); STAGE_B(1, 1, 1); STAGE_A(0, 1, 1); STAGE_A(1, 1, 1);
    asm volatile("s_waitcnt vmcnt(8)" ::: "memory");
    __builtin_amdgcn_s_barrier();

    for (int t = 0; t < NT; ++t) {
        const int cur = t & 1;
        const u16* Ab = As + cur * 16384;
        const u16* Bb = Bs + cur * 16384;
        const bool pf = (t + 2 < NT);

        // ---- R1: a-lo + b0 ; R2: b1 (issued up front; compiler counts lgkm)
        #pragma unroll
        for (int mf = 0; mf < 4; ++mf)
            #pragma unroll
            for (int ks = 0; ks < 2; ++ks)
                al[mf][ks] = *reinterpret_cast<const bf16x8*>(Ab + aoff[mf][ks]);
        #pragma unroll
        for (int nf = 0; nf < 2; ++nf)
            #pragma unroll
            for (int ks = 0; ks < 2; ++ks)
                b0[nf][ks] = *reinterpret_cast<const bf16x8*>(Bb + boff[nf][ks]);
        #pragma unroll
        for (int nf = 0; nf < 2; ++nf)
            #pragma unroll
            for (int ks = 0; ks < 2; ++ks)
                b1[nf][ks] = *reinterpret_cast<const bf16x8*>(Bb + 2048 + boff[nf][ks]);

        // ---- MFMA1: a-lo x b0
        __builtin_amdgcn_s_setprio(1);
        #pragma unroll
        for (int mf = 0; mf < 4; ++mf)
            #pragma unroll
            for (int nf = 0; nf < 2; ++nf)
                #pragma unroll
                for (int ks = 0; ks < 2; ++ks)
                    acc[mf][nf] = __builtin_amdgcn_mfma_f32_16x16x32_bf16(
                        al[mf][ks], b0[nf][ks], acc[mf][nf], 0, 0, 0);
        __builtin_amdgcn_s_setprio(0);

        // ---- R3: a-hi (overlaps MFMA2's issue window)
        #pragma unroll
        for (int mf = 0; mf < 4; ++mf)
            #pragma unroll
            for (int ks = 0; ks < 2; ++ks)
                ah[mf][ks] = *reinterpret_cast<const bf16x8*>(Ab + 4096 + aoff[mf][ks]);

        // ---- MFMA2: a-lo x b1
        __builtin_amdgcn_s_setprio(1);
        #pragma unroll
        for (int mf = 0; mf < 4; ++mf)
            #pragma unroll
            for (int nf = 0; nf < 2; ++nf)
                #pragma unroll
                for (int ks = 0; ks < 2; ++ks)
                    acc[mf][2 + nf] = __builtin_amdgcn_mfma_f32_16x16x32_bf16(
                        al[mf][ks], b1[nf][ks], acc[mf][2 + nf], 0, 0, 0);
        __builtin_amdgcn_s_setprio(0);

        // ---- all reads of buffer `cur` drained, then block-wide fence
        asm volatile("s_waitcnt lgkmcnt(0)" ::: "memory");
        __builtin_amdgcn_sched_barrier(0);
        __builtin_amdgcn_s_barrier();

        // ---- stage tile t+2 into cur (WAR-safe now)
        if (pf) {
            STAGE_B(0, t + 2, cur); STAGE_B(1, t + 2, cur);
            STAGE_A(0, t + 2, cur); STAGE_A(1, t + 2, cur);
        }

        // ---- MFMA3: a-hi x b1 ; MFMA4: a-hi x b0 (registers only)
        __builtin_amdgcn_s_setprio(1);
        #pragma unroll
        for (int mf = 0; mf < 4; ++mf)
            #pragma unroll
            for (int nf = 0; nf < 2; ++nf)
                #pragma unroll
                for (int ks = 0; ks < 2; ++ks)
                    acc[4 + mf][2 + nf] = __builtin_amdgcn_mfma_f32_16x16x32_bf16(
                        ah[mf][ks], b1[nf][ks], acc[4 + mf][2 + nf], 0, 0, 0);
        #pragma unroll
        for (int mf = 0; mf < 4; ++mf)
            #pragma unroll
            for (int nf = 0; nf < 2; ++nf)
                #pragma unroll
                for (int ks = 0; ks < 2; ++ks)
                    acc[4 + mf][nf] = __builtin_amdgcn_mfma_f32_16x16x32_bf16(
                        ah[mf][ks], b0[nf][ks], acc[4 + mf][nf], 0, 0, 0);
        __builtin_amdgcn_s_setprio(0);

        // ---- counted drain: leave tile t+2's 8 GLDs in flight; tile-end barrier
        if (pf) asm volatile("s_waitcnt vmcnt(8)" ::: "memory");
        else    asm volatile("s_waitcnt vmcnt(0)" ::: "memory");
        __builtin_amdgcn_s_barrier();
    }

    // ---- epilogue: bias, fp32 C, BN stats (col = lane&15 group; row = lk*4+r)
    #pragma unroll
    for (int nh = 0; nh < 2; ++nh)
        #pragma unroll
        for (int nf = 0; nf < 2; ++nf) {
            int n = nh * 2 + nf;
            int col = bn * 256 + wn * 64 + nh * 32 + nf * 16 + lr;
            float bv = bias[col];
            float s1 = 0.f, s2 = 0.f;
            #pragma unroll
            for (int m = 0; m < 8; ++m) {
                int rbase = bm * 256 + wm * 128 + (m >> 2) * 64 + (m & 3) * 16 + lk * 4;
                #pragma unroll
                for (int r = 0; r < 4; ++r) {
                    float v = acc[m][n][r] + bv;
                    C[(size_t)(rbase + r) * DIMD + col] = v;
                    s1 += v; s2 += v * v;
                }
            }
            s1 += __shfl_xor(s1, 16); s1 += __shfl_xor(s1, 32);
            s2 += __shfl_xor(s2, 16); s2 += __shfl_xor(s2, 32);
            if (lk == 0) {
                atomicAdd(&csum[col], s1);
                atomicAdd(&csum2[col], s2);
            }
        }
#undef STAGE_A
#undef STAGE_B
}

// ------- normalize + relu -> bf16 (layers 0..2); BN finalize fused; float4 -------
__global__ void k_norm(const float* __restrict__ H, const float* __restrict__ sum,
                       const float* __restrict__ sum2, const float* __restrict__ gamma,
                       const float* __restrict__ beta, u16* __restrict__ o) {
    int j = (blockIdx.x * 256 + threadIdx.x) * 4;
    int i0 = blockIdx.y * 128;
    float4 sm = *reinterpret_cast<const float4*>(sum + j);
    float4 s2 = *reinterpret_cast<const float4*>(sum2 + j);
    float4 gm = *reinterpret_cast<const float4*>(gamma + j);
    float4 bt = *reinterpret_cast<const float4*>(beta + j);
    float s[4], tt[4];
    #pragma unroll
    for (int c = 0; c < 4; ++c) {
        float mu = (&sm.x)[c] * (1.0f / DIMB);
        float var = (&s2.x)[c] * (1.0f / DIMB) - mu * mu;
        s[c] = (&gm.x)[c] * rsqrtf(var + 1e-5f);
        tt[c] = (&bt.x)[c] - mu * s[c];
    }
    for (int i = i0; i < i0 + 128; ++i) {
        float4 h = *reinterpret_cast<const float4*>(H + (size_t)i * DIMD + j);
        ushort4 r;
        #pragma unroll
        for (int c = 0; c < 4; ++c)
            (&r.x)[c] = f2bf(fmaxf((&h.x)[c] * s[c] + tt[c], 0.0f));
        *reinterpret_cast<ushort4*>(o + (size_t)i * DIMD + j) = r;
    }
}

// ------- layer 3: normalize + relu + exp in place, column exp-sums; float4 -------
__global__ void k_normexp(float* __restrict__ H, const float* __restrict__ sum,
                          const float* __restrict__ sum2, const float* __restrict__ gamma,
                          const float* __restrict__ beta, float* __restrict__ esum) {
    int j = (blockIdx.x * 256 + threadIdx.x) * 4;
    int i0 = blockIdx.y * 128;
    float4 sm = *reinterpret_cast<const float4*>(sum + j);
    float4 s2 = *reinterpret_cast<const float4*>(sum2 + j);
    float4 gm = *reinterpret_cast<const float4*>(gamma + j);
    float4 bt = *reinterpret_cast<const float4*>(beta + j);
    float s[4], tt[4], acc[4] = {0.f, 0.f, 0.f, 0.f};
    #pragma unroll
    for (int c = 0; c < 4; ++c) {
        float mu = (&sm.x)[c] * (1.0f / DIMB);
        float var = (&s2.x)[c] * (1.0f / DIMB) - mu * mu;
        s[c] = (&gm.x)[c] * rsqrtf(var + 1e-5f);
        tt[c] = (&bt.x)[c] - mu * s[c];
    }
    for (int i = i0; i < i0 + 128; ++i) {
        float4 h = *reinterpret_cast<const float4*>(H + (size_t)i * DIMD + j);
        #pragma unroll
        for (int c = 0; c < 4; ++c) {
            float e = __expf(fmaxf((&h.x)[c] * s[c] + tt[c], 0.0f));
            (&h.x)[c] = e;
            acc[c] += e;
        }
        *reinterpret_cast<float4*>(H + (size_t)i * DIMD + j) = h;
    }
    #pragma unroll
    for (int c = 0; c < 4; ++c) atomicAdd(&esum[j + c], acc[c]);
}

// ---------------- softmax divide, in place ----------------
__global__ void k_div(float* __restrict__ H, const float* __restrict__ esum) {
    int i = (blockIdx.x * 256 + threadIdx.x) * 4;
    float4 v = *reinterpret_cast<const float4*>(H + i);
    const float4 e = *reinterpret_cast<const float4*>(esum + (i & (DIMD - 1)));
    v.x /= e.x; v.y /= e.y; v.z /= e.z; v.w /= e.w;
    *reinterpret_cast<float4*>(H + i) = v;
}

extern "C" void kernel_launch(void* const* d_in, const int* in_sizes, int n_in,
                              void* d_out, int out_size, void* d_ws, size_t ws_size,
                              hipStream_t stream) {
    (void)in_sizes; (void)n_in; (void)out_size; (void)ws_size;
    const float* x     = (const float*)d_in[0];
    const float* W     = (const float*)d_in[1];
    const float* b     = (const float*)d_in[2];
    const float* gamma = (const float*)d_in[3];
    const float* beta  = (const float*)d_in[4];
    float* out = (float*)d_out;                       // doubles as H scratch (fp32 4096x4096)

    char* ws = (char*)d_ws;                               // ws >= 1 GiB (observed)
    u16*  Abf = (u16*)ws;                                 // 32 MiB activation bf16
    u16*  Wt4 = (u16*)(ws + (size_t)32 * 1024 * 1024);    // 4 x 32 MiB transposed weights
    float* stats = (float*)(ws + (size_t)160 * 1024 * 1024);
    // stats: per layer l: sum = stats + l*8192, sum2 = sum + 4096; esum = stats + 32768
    hipMemsetAsync(stats, 0, (4 * 8192 + 4096) * sizeof(float), stream);

    k_cvt<<<DIMB * DIMD / 1024, 256, 0, stream>>>(x, Abf);
    k_trans<<<dim3(64, 64, 4), 256, 0, stream>>>(W, Wt4);

    for (int l = 0; l < NLAYER; ++l) {
        float* sum = stats + l * 8192;
        float* sum2 = sum + 4096;
        k_gemm<<<dim3(16, 16), 512, 0, stream>>>(Abf, Wt4 + (size_t)l * DIMD * DIMD,
                                                 b + l * DIMD, out, sum, sum2);
        if (l < NLAYER - 1)
            k_norm<<<dim3(4, 32), 256, 0, stream>>>(out, sum, sum2,
                gamma + l * DIMD, beta + l * DIMD, Abf);
        else
            k_normexp<<<dim3(4, 32), 256, 0, stream>>>(out, sum, sum2,
                gamma + l * DIMD, beta + l * DIMD, stats + 32768);
    }
    k_div<<<DIMB * DIMD / 1024, 256, 0, stream>>>(out, stats + 32768);
}